// Round 6
// baseline (293.750 us; speedup 1.0000x reference)
//
#include <hip/hip_runtime.h>

// Problem constants (match reference setup_inputs)
constexpr int B       = 4;
constexpr int N_NODES = 1000000;
constexpr int N_ELEM  = 500000;
constexpr int N_GP    = 9;
constexpr int N_EN    = 8;

constexpr int EPB     = 28;                  // elements per 256-thread block
constexpr int TOTALGP = N_ELEM * N_GP;       // 4.5M gauss points
constexpr int OUTQ4   = TOTALGP * 3 / 4;     // float4s per batch: 3,375,000

// clang vector type usable with __builtin_nontemporal_*
using f32x4 = __attribute__((ext_vector_type(4))) float;

// ---- bf16 helpers (RNE) ----
__device__ __forceinline__ unsigned f2bf(float f) {
    unsigned u = __builtin_bit_cast(unsigned, f);
    unsigned r = u + 0x7fffu + ((u >> 16) & 1u);
    return r >> 16;
}
__device__ __forceinline__ float bflo(unsigned w) {
    return __builtin_bit_cast(float, w << 16);
}
__device__ __forceinline__ float bfhi(unsigned w) {
    return __builtin_bit_cast(float, w & 0xffff0000u);
}

// ---------------------------------------------------------------------------
// Pass 1: inputs [B][N_NODES][2] f32 -> tn [N_NODES] x uint4 (8 bf16/node).
// word b = bf16(x_b) | bf16(y_b)<<16. One 16B record per node.
// ---------------------------------------------------------------------------
__global__ __launch_bounds__(256) void transpose_nodes_bf16(
    const float* __restrict__ inputs,  // [B][N_NODES][2]
    uint4*       __restrict__ tn)      // [N_NODES]
{
    int n = blockIdx.x * blockDim.x + threadIdx.x;
    if (n >= N_NODES) return;
    const float2* in2 = reinterpret_cast<const float2*>(inputs);
    float2 a0 = in2[(size_t)0 * N_NODES + n];
    float2 a1 = in2[(size_t)1 * N_NODES + n];
    float2 a2 = in2[(size_t)2 * N_NODES + n];
    float2 a3 = in2[(size_t)3 * N_NODES + n];
    uint4 w;
    w.x = f2bf(a0.x) | (f2bf(a0.y) << 16);
    w.y = f2bf(a1.x) | (f2bf(a1.y) << 16);
    w.z = f2bf(a2.x) | (f2bf(a2.y) << 16);
    w.w = f2bf(a3.x) | (f2bf(a3.y) << 16);
    tn[n] = w;
}

// ---------------------------------------------------------------------------
// Pass 2: block-cooperative. 256 threads own EPB=28 elements.
//  phase 1: 224 threads fetch ONE (elem,node) 16B record each -> LDS
//           (9x fewer gather lanes + 9x fewer elem-index lanes than per-GP)
//  phase 2: 252 GP-threads consume records via LDS broadcast, FMA, -> LDS
//  phase 3: contiguous full-line float4 NT stores
// gbuf padded to stride 9 (float4 units): per-k read banks 4*(el+k)%32,
// el+k distinct mod 8 -> conflict-free broadcast.
// ---------------------------------------------------------------------------
__global__ __launch_bounds__(256, 8) void kinematic_lds(
    const uint4* __restrict__ tn,      // [N_NODES]
    const float* __restrict__ shpdx,   // [N_ELEM][N_GP][N_EN][2]
    const int*   __restrict__ elem,    // [N_ELEM][N_EN]
    float*       __restrict__ out)     // [B][TOTALGP][3]
{
    __shared__ uint4 gbuf[EPB * 9];          // 28*9*16B = 4032 B (stride-9 pad)
    __shared__ float obuf[B * EPB * 27];     // 4*756*4B  = 12096 B

    const int l  = threadIdx.x;
    const int e0 = blockIdx.x * EPB;
    const int nel = (N_ELEM - e0 < EPB) ? (N_ELEM - e0) : EPB;

    // ---- phase 1: one gather lane per (element, node) ----
    if (l < nel * N_EN) {
        const int el = l >> 3;
        const int k  = l & 7;
        const int nd = elem[(e0 + el) * N_EN + k];   // coalesced 1 dword/lane
        gbuf[el * 9 + k] = tn[nd];                   // random 16B gather
    }

    // ---- issue shpdx stream loads early (independent of LDS) ----
    const bool active = l < nel * N_GP;
    f32x4 s0 = {}, s1 = {}, s2 = {}, s3 = {};
    if (active) {
        const f32x4* sp = reinterpret_cast<const f32x4*>(shpdx)
                        + ((size_t)e0 * N_GP + l) * 4;
        s0 = __builtin_nontemporal_load(sp + 0);
        s1 = __builtin_nontemporal_load(sp + 1);
        s2 = __builtin_nontemporal_load(sp + 2);
        s3 = __builtin_nontemporal_load(sp + 3);
    }

    __syncthreads();

    // ---- phase 2: compute ----
    if (active) {
        const int el = l / N_GP;                 // magic-mul
        const float sx[8] = { s0[0], s0[2], s1[0], s1[2], s2[0], s2[2], s3[0], s3[2] };
        const float sy[8] = { s0[1], s0[3], s1[1], s1[3], s2[1], s2[3], s3[1], s3[3] };

        float axx[B] = {0.f, 0.f, 0.f, 0.f};
        float ayy[B] = {0.f, 0.f, 0.f, 0.f};
        float axy[B] = {0.f, 0.f, 0.f, 0.f};

        #pragma unroll
        for (int k = 0; k < 8; ++k) {
            uint4 g = gbuf[el * 9 + k];          // broadcast within element
            unsigned w0 = g.x, w1 = g.y, w2 = g.z, w3 = g.w;
            float dx[B] = { bflo(w0), bflo(w1), bflo(w2), bflo(w3) };
            float dy[B] = { bfhi(w0), bfhi(w1), bfhi(w2), bfhi(w3) };
            #pragma unroll
            for (int b = 0; b < B; ++b) {
                axx[b] = fmaf(sx[k], dx[b], axx[b]);
                ayy[b] = fmaf(sy[k], dy[b], ayy[b]);
                axy[b] = fmaf(sy[k], dx[b], fmaf(sx[k], dy[b], axy[b]));
            }
        }

        #pragma unroll
        for (int b = 0; b < B; ++b) {            // stride-3 writes: 2-way, free
            obuf[b * (EPB * 27) + l * 3 + 0] = axx[b];
            obuf[b * (EPB * 27) + l * 3 + 1] = ayy[b];
            obuf[b * (EPB * 27) + l * 3 + 2] = 0.5f * axy[b];
        }
    }

    __syncthreads();

    // ---- phase 3: full-line float4 NT stores ----
    const int q4 = (27 * nel) >> 2;              // f4 per batch (nel%4==0 always)
    const f32x4* ob4  = reinterpret_cast<const f32x4*>(obuf);
    f32x4*       out4 = reinterpret_cast<f32x4*>(out);
    const size_t base4 = (size_t)blockIdx.x * (EPB * 27 / 4);    // *189

    #pragma unroll
    for (int b = 0; b < B; ++b) {
        for (int w = l; w < q4; w += 256) {
            __builtin_nontemporal_store(ob4[b * (EPB * 27 / 4) + w],
                                        &out4[(size_t)b * OUTQ4 + base4 + w]);
        }
    }
}

// ---------------------------------------------------------------------------
// Fallback (no-workspace path): direct f32 gathers from original layout.
// ---------------------------------------------------------------------------
__global__ __launch_bounds__(256) void kinematic_kernel(
    const float* __restrict__ inputs,
    const float* __restrict__ shpdx,
    const int*   __restrict__ elem,
    float*       __restrict__ out)
{
    const int total = N_ELEM * N_GP;
    int tid = blockIdx.x * blockDim.x + threadIdx.x;
    if (tid >= total) return;

    int e = tid / N_GP;

    const float4* sp = reinterpret_cast<const float4*>(shpdx) + (size_t)tid * 4;
    float4 s0 = sp[0];
    float4 s1 = sp[1];
    float4 s2 = sp[2];
    float4 s3 = sp[3];
    float sx[8] = { s0.x, s0.z, s1.x, s1.z, s2.x, s2.z, s3.x, s3.z };
    float sy[8] = { s0.y, s0.w, s1.y, s1.w, s2.y, s2.w, s3.y, s3.w };

    const int4* ep = reinterpret_cast<const int4*>(elem + (size_t)e * N_EN);
    int4 n0 = ep[0];
    int4 n1 = ep[1];
    int nd[8] = { n0.x, n0.y, n0.z, n0.w, n1.x, n1.y, n1.z, n1.w };

    #pragma unroll
    for (int b = 0; b < B; ++b) {
        const float2* inb = reinterpret_cast<const float2*>(inputs) + (size_t)b * N_NODES;
        float2 d[8];
        #pragma unroll
        for (int k = 0; k < 8; ++k) d[k] = inb[nd[k]];

        float axx = 0.f, ayy = 0.f, axy = 0.f;
        #pragma unroll
        for (int k = 0; k < 8; ++k) {
            axx = fmaf(sx[k], d[k].x, axx);
            ayy = fmaf(sy[k], d[k].y, ayy);
            axy = fmaf(sy[k], d[k].x, fmaf(sx[k], d[k].y, axy));
        }

        size_t o = ((size_t)b * total + (size_t)tid) * 3;
        out[o + 0] = axx;
        out[o + 1] = ayy;
        out[o + 2] = 0.5f * axy;
    }
}

extern "C" void kernel_launch(void* const* d_in, const int* in_sizes, int n_in,
                              void* d_out, int out_size, void* d_ws, size_t ws_size,
                              hipStream_t stream) {
    const float* inputs = (const float*)d_in[0];  // [B, N_NODES, 2]
    const float* shpdx  = (const float*)d_in[1];  // [N_ELEM, N_GP, 8, 2]
    const int*   elem   = (const int*)d_in[2];    // [N_ELEM, 8]
    float* out = (float*)d_out;                   // [B, N_ELEM*N_GP, 3]

    const int block = 256;
    const size_t tn_bytes = (size_t)N_NODES * sizeof(uint4); // 16 MB

    if (ws_size >= tn_bytes) {
        uint4* tn = (uint4*)d_ws;
        transpose_nodes_bf16<<<(N_NODES + block - 1) / block, block, 0, stream>>>(inputs, tn);
        const int grid = (N_ELEM + EPB - 1) / EPB;           // 17,858 blocks
        kinematic_lds<<<grid, block, 0, stream>>>(tn, shpdx, elem, out);
    } else {
        const int total = N_ELEM * N_GP;
        const int grid  = (total + block - 1) / block;
        kinematic_kernel<<<grid, block, 0, stream>>>(inputs, shpdx, elem, out);
    }
}

// Round 7
// 162.887 us; speedup vs baseline: 1.8034x; 1.8034x over previous
//
#include <hip/hip_runtime.h>

// Problem constants (match reference setup_inputs)
constexpr int B       = 4;
constexpr int N_NODES = 1000000;
constexpr int N_ELEM  = 500000;
constexpr int N_GP    = 9;
constexpr int N_EN    = 8;

constexpr int BLK     = 512;                 // threads per block
constexpr int EPB     = 48;                  // elements per block
                                             // per-batch out span: 48*27*4B = 5184B = 81 lines (aligned!)
constexpr int TOTALGP = N_ELEM * N_GP;       // 4.5M gauss points
constexpr int OUTQ4   = TOTALGP * 3 / 4;     // float4s per batch: 3,375,000

// clang vector type usable with __builtin_nontemporal_*
using f32x4 = __attribute__((ext_vector_type(4))) float;

// ---- bf16 helpers (RNE) ----
__device__ __forceinline__ unsigned f2bf(float f) {
    unsigned u = __builtin_bit_cast(unsigned, f);
    unsigned r = u + 0x7fffu + ((u >> 16) & 1u);
    return r >> 16;
}
__device__ __forceinline__ float bflo(unsigned w) {
    return __builtin_bit_cast(float, w << 16);
}
__device__ __forceinline__ float bfhi(unsigned w) {
    return __builtin_bit_cast(float, w & 0xffff0000u);
}

// ---------------------------------------------------------------------------
// Pass 1: inputs [B][N_NODES][2] f32 -> tn [N_NODES] x uint4 (8 bf16/node).
// ---------------------------------------------------------------------------
__global__ __launch_bounds__(256) void transpose_nodes_bf16(
    const float* __restrict__ inputs,  // [B][N_NODES][2]
    uint4*       __restrict__ tn)      // [N_NODES]
{
    int n = blockIdx.x * blockDim.x + threadIdx.x;
    if (n >= N_NODES) return;
    const float2* in2 = reinterpret_cast<const float2*>(inputs);
    float2 a0 = in2[(size_t)0 * N_NODES + n];
    float2 a1 = in2[(size_t)1 * N_NODES + n];
    float2 a2 = in2[(size_t)2 * N_NODES + n];
    float2 a3 = in2[(size_t)3 * N_NODES + n];
    uint4 w;
    w.x = f2bf(a0.x) | (f2bf(a0.y) << 16);
    w.y = f2bf(a1.x) | (f2bf(a1.y) << 16);
    w.z = f2bf(a2.x) | (f2bf(a2.y) << 16);
    w.w = f2bf(a3.x) | (f2bf(a3.y) << 16);
    tn[n] = w;
}

// ---------------------------------------------------------------------------
// Pass 2: block-cooperative, 512 threads own EPB=48 elements.
//  phase 1: 384 threads fetch ONE (elem,node) 16B record each -> LDS
//  phase 2: 432 GP-threads consume via LDS broadcast, FMA, -> LDS
//  phase 3: plain full-line float4 stores (spans exactly line-aligned)
// ---------------------------------------------------------------------------
__global__ __launch_bounds__(512) void kinematic_lds(
    const uint4* __restrict__ tn,      // [N_NODES]
    const float* __restrict__ shpdx,   // [N_ELEM][N_GP][N_EN][2]
    const int*   __restrict__ elem,    // [N_ELEM][N_EN]
    float*       __restrict__ out)     // [B][TOTALGP][3]
{
    __shared__ uint4 gbuf[EPB * 9];          // 48*9*16B = 6912 B (stride-9 pad)
    __shared__ float obuf[B * EPB * 27];     // 4*1296*4B = 20736 B

    const int l  = threadIdx.x;
    const int e0 = blockIdx.x * EPB;
    const int nel = (N_ELEM - e0 < EPB) ? (N_ELEM - e0) : EPB;  // 48 or 32

    // ---- phase 1: one gather lane per (element, node) ----
    if (l < nel * N_EN) {
        const int el = l >> 3;
        const int k  = l & 7;
        const int nd = elem[(e0 + el) * N_EN + k];   // coalesced 1 dword/lane
        gbuf[el * 9 + k] = tn[nd];                   // random 16B gather
    }

    // ---- issue shpdx stream loads early (independent of LDS); nt = evict-first
    const bool active = l < nel * N_GP;
    f32x4 s0 = {}, s1 = {}, s2 = {}, s3 = {};
    if (active) {
        const f32x4* sp = reinterpret_cast<const f32x4*>(shpdx)
                        + ((size_t)e0 * N_GP + l) * 4;
        s0 = __builtin_nontemporal_load(sp + 0);
        s1 = __builtin_nontemporal_load(sp + 1);
        s2 = __builtin_nontemporal_load(sp + 2);
        s3 = __builtin_nontemporal_load(sp + 3);
    }

    __syncthreads();

    // ---- phase 2: compute ----
    if (active) {
        const int el = l / N_GP;                 // magic-mul
        const float sx[8] = { s0[0], s0[2], s1[0], s1[2], s2[0], s2[2], s3[0], s3[2] };
        const float sy[8] = { s0[1], s0[3], s1[1], s1[3], s2[1], s2[3], s3[1], s3[3] };

        float axx[B] = {0.f, 0.f, 0.f, 0.f};
        float ayy[B] = {0.f, 0.f, 0.f, 0.f};
        float axy[B] = {0.f, 0.f, 0.f, 0.f};

        #pragma unroll
        for (int k = 0; k < 8; ++k) {
            uint4 g = gbuf[el * 9 + k];          // broadcast within element
            unsigned w0 = g.x, w1 = g.y, w2 = g.z, w3 = g.w;
            float dx[B] = { bflo(w0), bflo(w1), bflo(w2), bflo(w3) };
            float dy[B] = { bfhi(w0), bfhi(w1), bfhi(w2), bfhi(w3) };
            #pragma unroll
            for (int b = 0; b < B; ++b) {
                axx[b] = fmaf(sx[k], dx[b], axx[b]);
                ayy[b] = fmaf(sy[k], dy[b], ayy[b]);
                axy[b] = fmaf(sy[k], dx[b], fmaf(sx[k], dy[b], axy[b]));
            }
        }

        #pragma unroll
        for (int b = 0; b < B; ++b) {            // stride-3 writes: 2-way, free
            obuf[b * (EPB * 27) + l * 3 + 0] = axx[b];
            obuf[b * (EPB * 27) + l * 3 + 1] = ayy[b];
            obuf[b * (EPB * 27) + l * 3 + 2] = 0.5f * axy[b];
        }
    }

    __syncthreads();

    // ---- phase 3: plain full-line float4 stores, line-aligned spans ----
    const int q4 = (27 * nel) >> 2;              // 324 (or 216 tail); nel%4==0
    const float4* ob4  = reinterpret_cast<const float4*>(obuf);
    float4*       out4 = reinterpret_cast<float4*>(out);
    const size_t  base4 = (size_t)blockIdx.x * (EPB * 27 / 4);   // *324

    #pragma unroll
    for (int b = 0; b < B; ++b) {
        if (l < q4)
            out4[(size_t)b * OUTQ4 + base4 + l] = ob4[b * (EPB * 27 / 4) + l];
    }
}

// ---------------------------------------------------------------------------
// Fallback (no-workspace path): direct f32 gathers from original layout.
// ---------------------------------------------------------------------------
__global__ __launch_bounds__(256) void kinematic_kernel(
    const float* __restrict__ inputs,
    const float* __restrict__ shpdx,
    const int*   __restrict__ elem,
    float*       __restrict__ out)
{
    const int total = N_ELEM * N_GP;
    int tid = blockIdx.x * blockDim.x + threadIdx.x;
    if (tid >= total) return;

    int e = tid / N_GP;

    const float4* sp = reinterpret_cast<const float4*>(shpdx) + (size_t)tid * 4;
    float4 s0 = sp[0];
    float4 s1 = sp[1];
    float4 s2 = sp[2];
    float4 s3 = sp[3];
    float sx[8] = { s0.x, s0.z, s1.x, s1.z, s2.x, s2.z, s3.x, s3.z };
    float sy[8] = { s0.y, s0.w, s1.y, s1.w, s2.y, s2.w, s3.y, s3.w };

    const int4* ep = reinterpret_cast<const int4*>(elem + (size_t)e * N_EN);
    int4 n0 = ep[0];
    int4 n1 = ep[1];
    int nd[8] = { n0.x, n0.y, n0.z, n0.w, n1.x, n1.y, n1.z, n1.w };

    #pragma unroll
    for (int b = 0; b < B; ++b) {
        const float2* inb = reinterpret_cast<const float2*>(inputs) + (size_t)b * N_NODES;
        float2 d[8];
        #pragma unroll
        for (int k = 0; k < 8; ++k) d[k] = inb[nd[k]];

        float axx = 0.f, ayy = 0.f, axy = 0.f;
        #pragma unroll
        for (int k = 0; k < 8; ++k) {
            axx = fmaf(sx[k], d[k].x, axx);
            ayy = fmaf(sy[k], d[k].y, ayy);
            axy = fmaf(sy[k], d[k].x, fmaf(sx[k], d[k].y, axy));
        }

        size_t o = ((size_t)b * total + (size_t)tid) * 3;
        out[o + 0] = axx;
        out[o + 1] = ayy;
        out[o + 2] = 0.5f * axy;
    }
}

extern "C" void kernel_launch(void* const* d_in, const int* in_sizes, int n_in,
                              void* d_out, int out_size, void* d_ws, size_t ws_size,
                              hipStream_t stream) {
    const float* inputs = (const float*)d_in[0];  // [B, N_NODES, 2]
    const float* shpdx  = (const float*)d_in[1];  // [N_ELEM, N_GP, 8, 2]
    const int*   elem   = (const int*)d_in[2];    // [N_ELEM, 8]
    float* out = (float*)d_out;                   // [B, N_ELEM*N_GP, 3]

    const size_t tn_bytes = (size_t)N_NODES * sizeof(uint4); // 16 MB

    if (ws_size >= tn_bytes) {
        uint4* tn = (uint4*)d_ws;
        transpose_nodes_bf16<<<(N_NODES + 255) / 256, 256, 0, stream>>>(inputs, tn);
        const int grid = (N_ELEM + EPB - 1) / EPB;           // 10,417 blocks
        kinematic_lds<<<grid, BLK, 0, stream>>>(tn, shpdx, elem, out);
    } else {
        const int total = N_ELEM * N_GP;
        const int grid  = (total + 255) / 256;
        kinematic_kernel<<<grid, 256, 0, stream>>>(inputs, shpdx, elem, out);
    }
}